// Round 1
// 1732.947 us; speedup vs baseline: 1.0107x; 1.0107x over previous
//
#include <hip/hip_runtime.h>

// ---------------------------------------------------------------------------
// VectorQuantize: conv1d(s2) x2 -> l2norm -> nearest-codebook argmax
// Round 5: score_top2 rebuilt on the m97 GEMM structure:
//   - pure global_load_lds (width 16) staging into linear [128][64] LDS tiles
//   - bank-conflict-free ds_read via source-side XOR swizzle (group ^= row&7),
//     pre-applied when norm_rows/norm_cb emit enc16/cbn16
//   - 32 KB LDS/block (was 36.8 KB), no staging VALU/registers
// Conv + rescore stages unchanged. Workspace required: ~331 MiB.
// ---------------------------------------------------------------------------

typedef __attribute__((ext_vector_type(8))) _Float16 f16x8;
typedef __attribute__((ext_vector_type(8))) short bf16x8;
typedef __attribute__((ext_vector_type(4))) float f32x4;

__device__ inline ushort f2bf(float x) {
  union { float f; unsigned u; } v; v.f = x;
  unsigned r = v.u + 0x7fffu + ((v.u >> 16) & 1u);
  return (ushort)(r >> 16);
}

__device__ inline void splitf(float v, ushort& h, ushort& l) {
  union { _Float16 h; ushort u; } a, b;
  a.h = (_Float16)v;
  b.h = (_Float16)(v - (float)a.h);
  h = a.u; l = b.u;
}

// async global->LDS, 16B per lane; lds dst = base + lane*16 (linear).
__device__ inline void gload_lds16(const ushort* g, ushort* l) {
  __builtin_amdgcn_global_load_lds(
      (const __attribute__((address_space(1))) unsigned int*)g,
      (__attribute__((address_space(3))) unsigned int*)l, 16, 0, 0);
}

// Split w[co][ci][3] fp32 -> ws[koff*2+part][co][ci] fp16.
__global__ __launch_bounds__(256) void prep_w(const float* __restrict__ w,
                                              ushort* __restrict__ ws,
                                              int n /* 512*cin */) {
  const int idx = blockIdx.x * 256 + threadIdx.x;
  if (idx >= n) return;
  const float v0 = w[(size_t)idx * 3 + 0];
  const float v1 = w[(size_t)idx * 3 + 1];
  const float v2 = w[(size_t)idx * 3 + 2];
  ushort h, l;
  splitf(v0, h, l); ws[idx] = h; ws[(size_t)n + idx] = l;
  splitf(v1, h, l); ws[2 * (size_t)n + idx] = h; ws[3 * (size_t)n + idx] = l;
  splitf(v2, h, l); ws[4 * (size_t)n + idx] = h; ws[5 * (size_t)n + idx] = l;
}

// Zero the odd-phase guard rows (t=-1) for both conv inputs.
__global__ __launch_bounds__(256) void zero_halo(ushort* __restrict__ xo1,
                                                 ushort* __restrict__ xo2) {
  const int b = blockIdx.x, tid = threadIdx.x;
  const uint4 z = make_uint4(0, 0, 0, 0);
  *(uint4*)(xo1 + (size_t)b * 2049 * 2048 + tid * 8) = z;
  if (tid < 128) *(uint4*)(xo2 + (size_t)b * 1025 * 1024 + tid * 8) = z;
}

// x[b][ci][T] fp32 -> phase-split fp16 hi/lo:
//   xe[b][t=0..T/2-1][ch][part][ci32]  (x[2t])
//   xo[b][row=1..T/2][ch][part][ci32]  (x[2row-1]; row 0 = zero guard)
template <int CI, int T>
__global__ __launch_bounds__(256) void prep_x(const float* __restrict__ x,
                                              ushort* __restrict__ xe,
                                              ushort* __restrict__ xo) {
  const int t0 = blockIdx.x * 256;
  const int ci0 = blockIdx.y * 32;
  const int b = blockIdx.z;
  const int tid = threadIdx.x;
  __shared__ float tile[32][257];
  const int wv = tid >> 6, lane = tid & 63;
  const float* xb = x + ((size_t)b * CI + ci0) * T + t0;
#pragma unroll
  for (int r = 0; r < 8; r++) {
    const int ci = r * 4 + wv;
    const float4 v = *(const float4*)(xb + (size_t)ci * T + lane * 4);
    tile[ci][lane * 4 + 0] = v.x; tile[ci][lane * 4 + 1] = v.y;
    tile[ci][lane * 4 + 2] = v.z; tile[ci][lane * 4 + 3] = v.w;
  }
  __syncthreads();
  const int jj = tid >> 1, ph = tid & 1;  // tl = tid: 2-way LDS reads (free)
  const int tl = 2 * jj + ph;
  __attribute__((aligned(16))) ushort h[32], l[32];
#pragma unroll
  for (int c = 0; c < 32; c++) splitf(tile[c][tl], h[c], l[c]);
  constexpr int TH = T / 2;
  constexpr int RW = CI * 2;  // ushorts per row
  ushort* dst;
  if (ph == 0) dst = xe + ((size_t)b * TH + (t0 >> 1) + jj) * RW;
  else dst = xo + ((size_t)b * (TH + 1) + (t0 >> 1) + jj + 1) * RW;
  dst += (ci0 >> 5) * 64;
#pragma unroll
  for (int k = 0; k < 4; k++) {
    *(uint4*)(dst + k * 8) = *(const uint4*)(h + k * 8);
    *(uint4*)(dst + 32 + k * 8) = *(const uint4*)(l + k * 8);
  }
}

// Conv1d stride2 pad1 k3 on fp16-split MFMA (hh+hl+lh), pre-split inputs.
// Block: 128co x 64t, 4 waves (each 32co x 64t). 4 blocks/CU.
// SPLIT_OUT: write output split into conv2's input layout (ye/yo);
// else write fp32 out[(b t)][512].
template <int C_IN, int T_OUT, bool SPLIT_OUT>
__global__ __launch_bounds__(256, 4) void conv_mfma(
    const ushort* __restrict__ xe, const ushort* __restrict__ xo,
    const ushort* __restrict__ ws, float* __restrict__ out,
    ushort* __restrict__ ye, ushort* __restrict__ yo) {
  const int co0 = blockIdx.x * 128;
  const int t0 = blockIdx.y * 64;
  const int b = blockIdx.z;
  const int tid = threadIdx.x;
  const int wv = tid >> 6, lane = tid & 63;
  const int l15 = lane & 15, quad = lane >> 4;

  // PX=40 ushorts: 80B row stride -> b128 frag reads 2-way (free), 16B aligned
  __shared__ ushort xeh[64 * 40], xel[64 * 40], xoh[65 * 40], xol[65 * 40];

  f32x4 acc[2][4] = {};
  const int RW = C_IN * 2;
  const ushort* xe_b = xe + ((size_t)b * T_OUT + t0) * RW;
  const ushort* xo_b = xo + ((size_t)b * (T_OUT + 1) + t0) * RW;

  for (int ci0 = 0; ci0 < C_IN; ci0 += 32) {
    __syncthreads();
    const int choff = (ci0 >> 5) * 64;
    // stage: 258 row-part units x 4 groups of 16B = 1032 lane-tasks
#pragma unroll
    for (int q = 0; q < 5; q++) {
      const int id = tid + 256 * q;
      if (id < 1032) {
        const int g = id & 3;
        const int u = id >> 2;
        const uint4* src;
        ushort* dst;
        if (u < 128) {
          const int row = u >> 1, part = u & 1;
          src = (const uint4*)(xe_b + (size_t)row * RW + choff + part * 32 + g * 8);
          dst = (part ? xel : xeh) + row * 40 + g * 8;
        } else {
          const int u2 = u - 128;
          const int row = u2 >> 1, part = u2 & 1;
          src = (const uint4*)(xo_b + (size_t)row * RW + choff + part * 32 + g * 8);
          dst = (part ? xol : xoh) + row * 40 + g * 8;
        }
        *(uint4*)dst = *src;
      }
    }
    __syncthreads();

#pragma unroll
    for (int koff = 0; koff < 3; koff++) {
      // A (W) fragments straight from global (L2/L3-resident)
      f16x8 a_h[2], a_l[2];
#pragma unroll
      for (int i = 0; i < 2; i++) {
        const size_t co = (size_t)co0 + wv * 32 + i * 16 + l15;
        const ushort* wp = ws + ((size_t)(koff * 2) * 512) * C_IN + co * C_IN + ci0 + quad * 8;
        a_h[i] = *(const f16x8*)wp;
        a_l[i] = *(const f16x8*)(wp + (size_t)512 * C_IN);
      }
      const ushort* bh = (koff == 1) ? xeh : xoh;
      const ushort* bl = (koff == 1) ? xel : xol;
      const int radd = (koff == 2) ? 1 : 0;
#pragma unroll
      for (int j = 0; j < 4; j++) {
        const int row = j * 16 + l15 + radd;
        const f16x8 b_h = *(const f16x8*)(bh + row * 40 + quad * 8);
        const f16x8 b_l = *(const f16x8*)(bl + row * 40 + quad * 8);
#pragma unroll
        for (int i = 0; i < 2; i++) {
          acc[i][j] = __builtin_amdgcn_mfma_f32_16x16x32_f16(a_h[i], b_h, acc[i][j], 0, 0, 0);
          acc[i][j] = __builtin_amdgcn_mfma_f32_16x16x32_f16(a_h[i], b_l, acc[i][j], 0, 0, 0);
          acc[i][j] = __builtin_amdgcn_mfma_f32_16x16x32_f16(a_l[i], b_h, acc[i][j], 0, 0, 0);
        }
      }
    }
  }

  if (SPLIT_OUT) {
    // write split fp16 into conv2's input layout (C=512 -> row = 1024 ush)
#pragma unroll
    for (int i = 0; i < 2; i++) {
      const int ch = (co0 >> 5) + wv;
      const int ci32 = i * 16 + quad * 4;
#pragma unroll
      for (int j = 0; j < 4; j++) {
        const int t = t0 + j * 16 + l15;
        const int ph = t & 1;
        const int row = (t >> 1) + ph;  // even -> ye[t/2]; odd -> yo[(t/2)+1]
        __attribute__((aligned(8))) ushort h[4], l[4];
#pragma unroll
        for (int r = 0; r < 4; r++) splitf(acc[i][j][r], h[r], l[r]);
        ushort* dst = (ph ? yo : ye) +
                      ((size_t)b * (ph ? 1025 : 1024) + row) * 1024 + ch * 64 + ci32;
        *(uint2*)dst = *(const uint2*)h;
        *(uint2*)(dst + 32) = *(const uint2*)l;
      }
    }
  } else {
#pragma unroll
    for (int i = 0; i < 2; i++) {
#pragma unroll
      for (int j = 0; j < 4; j++) {
        const int t = t0 + j * 16 + l15;
        const int co = co0 + wv * 32 + i * 16 + quad * 4;
        const float4 v = make_float4(acc[i][j][0], acc[i][j][1], acc[i][j][2], acc[i][j][3]);
        *(float4*)(out + ((size_t)b * T_OUT + t) * 512 + co) = v;
      }
    }
  }
}

// Row-wise L2 normalize: out2t[(b t)][512] -> enc fp32 + enc16 bf16.
// enc16 is written PRE-SWIZZLED for score_top2's LDS staging:
// within each 64-ushort chunk, 8-ushort group g is stored at g ^ (row&7).
__global__ __launch_bounds__(64) void norm_rows(const float* __restrict__ out2t,
                                                float* __restrict__ enc,
                                                ushort* __restrict__ enc16) {
  const int row = blockIdx.x;
  const int lane = threadIdx.x;
  const float* p = out2t + (size_t)row * 512 + lane * 8;
  const float4 v0 = *(const float4*)p;
  const float4 v1 = *(const float4*)(p + 4);
  float ss = v0.x * v0.x + v0.y * v0.y + v0.z * v0.z + v0.w * v0.w +
             v1.x * v1.x + v1.y * v1.y + v1.z * v1.z + v1.w * v1.w;
#pragma unroll
  for (int m = 32; m >= 1; m >>= 1) ss += __shfl_xor(ss, m, 64);
  const float inv = 1.0f / fmaxf(sqrtf(ss), 1e-12f);
  float4 a, c;
  a.x = v0.x * inv; a.y = v0.y * inv; a.z = v0.z * inv; a.w = v0.w * inv;
  c.x = v1.x * inv; c.y = v1.y * inv; c.z = v1.z * inv; c.w = v1.w * inv;
  float* eo = enc + (size_t)row * 512 + lane * 8;
  *(float4*)eo = a;
  *(float4*)(eo + 4) = c;
  __attribute__((aligned(16))) ushort u[8] = {
      f2bf(a.x), f2bf(a.y), f2bf(a.z), f2bf(a.w),
      f2bf(c.x), f2bf(c.y), f2bf(c.z), f2bf(c.w)};
  // lane covers group (lane&7) of chunk (lane>>3): swizzle group by row&7
  const int sidx = (lane & 56) | ((lane ^ row) & 7);
  *(uint4*)(enc16 + (size_t)row * 512 + sidx * 8) = *(const uint4*)u;
}

// Normalize codebook rows (fp32 + bf16) and emit sum(cbn^2).
// cbn16 written pre-swizzled (same scheme as enc16).
__global__ __launch_bounds__(256) void norm_cb(const float* __restrict__ cb,
                                               float* __restrict__ cbn,
                                               ushort* __restrict__ cbn16,
                                               float* __restrict__ cb2) {
  const int row = blockIdx.x * 4 + (threadIdx.x >> 6);
  const int lane = threadIdx.x & 63;
  const float* p = cb + (long)row * 512;
  const float4 v0 = *(const float4*)(p + lane * 4);
  const float4 v1 = *(const float4*)(p + 256 + lane * 4);
  float ss = v0.x * v0.x + v0.y * v0.y + v0.z * v0.z + v0.w * v0.w +
             v1.x * v1.x + v1.y * v1.y + v1.z * v1.z + v1.w * v1.w;
#pragma unroll
  for (int m = 32; m >= 1; m >>= 1) ss += __shfl_xor(ss, m, 64);
  const float n = fmaxf(sqrtf(ss), 1e-12f);
  float4 a, c;
  a.x = v0.x / n; a.y = v0.y / n; a.z = v0.z / n; a.w = v0.w / n;
  c.x = v1.x / n; c.y = v1.y / n; c.z = v1.z / n; c.w = v1.w / n;
  *(float4*)(cbn + (long)row * 512 + lane * 4) = a;
  *(float4*)(cbn + (long)row * 512 + 256 + lane * 4) = c;
  ushort4 ua, uc;
  ua.x = f2bf(a.x); ua.y = f2bf(a.y); ua.z = f2bf(a.z); ua.w = f2bf(a.w);
  uc.x = f2bf(c.x); uc.y = f2bf(c.y); uc.z = f2bf(c.z); uc.w = f2bf(c.w);
  const int idx0 = lane * 4;
  const int idx1 = 256 + lane * 4;
  const int s0 = (idx0 & ~56) | ((((idx0 >> 3) ^ row) & 7) << 3);
  const int s1 = (idx1 & ~56) | ((((idx1 >> 3) ^ row) & 7) << 3);
  *(ushort4*)(cbn16 + (long)row * 512 + s0) = ua;
  *(ushort4*)(cbn16 + (long)row * 512 + s1) = uc;
  float s2 = a.x * a.x + a.y * a.y + a.z * a.z + a.w * a.w +
             c.x * c.x + c.y * c.y + c.z * c.z + c.w * c.w;
#pragma unroll
  for (int m = 32; m >= 1; m >>= 1) s2 += __shfl_xor(s2, m, 64);
  if (lane == 0) cb2[row] = s2;
}

__device__ inline void top2_merge(float& s1, int& i1, float& s2, int& i2,
                                  float t1, int j1, float t2, int j2) {
  if (t1 > s1) {
    if (s1 > t2) { s2 = s1; i2 = i1; } else { s2 = t2; i2 = j2; }
    s1 = t1; i1 = j1;
  } else if (t1 > s2) {
    s2 = t1; i2 = j1;
  }
}

// 128x128 bf16 MFMA GEMM tile (m97 structure): global_load_lds staging into
// linear [128][64] LDS tiles; bank-conflict-free reads via the source-side
// XOR swizzle (group ^= row&7) baked into enc16/cbn16.
// approx score = 2*dot - |cb|^2, fused per-wave per-row top-2
// -> 4 candidates/row/block.
__global__ __launch_bounds__(256) void score_top2(
    const ushort* __restrict__ enc16, const ushort* __restrict__ cbn16,
    const float* __restrict__ cb2, float* __restrict__ pscore,
    int* __restrict__ pidx) {
  const int nt = blockIdx.x;
  const int mt = blockIdx.y;
  const int m0 = mt * 128, n0 = nt * 128;
  const int tid = threadIdx.x;
  const int wave = tid >> 6, lane = tid & 63;
  const int wm = wave & 1, wn = wave >> 1;
  const int quad = lane >> 4, l15 = lane & 15;

  __shared__ __attribute__((aligned(16))) ushort a_s[128 * 64];
  __shared__ __attribute__((aligned(16))) ushort b_s[128 * 64];

  f32x4 acc[4][4] = {};

  // staging geometry: one gload_lds16 stages 8 rows x 64 ushorts (1 KB/wave)
  const int srow = lane >> 3;  // row within 8-row unit
  const int sgrp = lane & 7;   // 16B group within row
  const ushort* ag = enc16 + ((size_t)(m0 + wave * 32 + srow) * 512) + sgrp * 8;
  const ushort* bg = cbn16 + ((size_t)(n0 + wave * 32 + srow) * 512) + sgrp * 8;
  ushort* al = a_s + (wave * 32 + srow) * 64;  // lane*16B from wave base
  ushort* bl = b_s + (wave * 32 + srow) * 64;
  (void)al; (void)bl;

  for (int k0 = 0; k0 < 512; k0 += 64) {
    __syncthreads();  // all waves done reading previous tile
#pragma unroll
    for (int it = 0; it < 4; it++) {
      gload_lds16(ag + (size_t)(it * 8) * 512 + k0, a_s + (wave * 32 + it * 8) * 64);
      gload_lds16(bg + (size_t)(it * 8) * 512 + k0, b_s + (wave * 32 + it * 8) * 64);
    }
    __syncthreads();  // vmcnt(0) drain: tile resident

#pragma unroll
    for (int kk = 0; kk < 2; kk++) {
      bf16x8 af[4], bf[4];
#pragma unroll
      for (int i = 0; i < 4; i++) {
        const int r = wm * 64 + i * 16 + l15;
        af[i] = *(const bf16x8*)(a_s + r * 64 + (((kk * 4 + quad) ^ (l15 & 7)) * 8));
      }
#pragma unroll
      for (int j = 0; j < 4; j++) {
        const int r = wn * 64 + j * 16 + l15;
        bf[j] = *(const bf16x8*)(b_s + r * 64 + (((kk * 4 + quad) ^ (l15 & 7)) * 8));
      }
#pragma unroll
      for (int i = 0; i < 4; i++)
#pragma unroll
        for (int j = 0; j < 4; j++)
          acc[i][j] = __builtin_amdgcn_mfma_f32_16x16x32_bf16(af[i], bf[j], acc[i][j], 0, 0, 0);
    }
  }

  float cb2c[4];
  int coln[4];
#pragma unroll
  for (int j = 0; j < 4; j++) {
    coln[j] = n0 + wn * 64 + j * 16 + l15;
    cb2c[j] = cb2[coln[j]];
  }

#pragma unroll
  for (int mi = 0; mi < 4; mi++) {
#pragma unroll
    for (int i = 0; i < 4; i++) {
      float s1 = -3.4e38f, s2 = -3.4e38f;
      int i1 = -1, i2 = -1;
#pragma unroll
      for (int j = 0; j < 4; j++) {
        const float s = 2.0f * acc[mi][j][i] - cb2c[j];
        if (s > s1) { s2 = s1; i2 = i1; s1 = s; i1 = coln[j]; }
        else if (s > s2) { s2 = s; i2 = coln[j]; }
      }
#pragma unroll
      for (int m = 8; m >= 1; m >>= 1) {
        const float t1 = __shfl_xor(s1, m, 64);
        const int j1 = __shfl_xor(i1, m, 64);
        const float t2 = __shfl_xor(s2, m, 64);
        const int j2 = __shfl_xor(i2, m, 64);
        top2_merge(s1, i1, s2, i2, t1, j1, t2, j2);
      }
      if (l15 == 0) {
        const int row_g = m0 + wm * 64 + mi * 16 + quad * 4 + i;
        const size_t base = (size_t)row_g * 256 + (size_t)nt * 4 + wn * 2;
        pscore[base] = s1; pidx[base] = i1;
        pscore[base + 1] = s2; pidx[base + 1] = i2;
      }
    }
  }
}

// Per row: approx top-8 of 256 candidates, exact fp32 rescore, argmax.
__global__ __launch_bounds__(256) void rescore_argmax(
    const float* __restrict__ enc, const float* __restrict__ cbn,
    const float* __restrict__ cb2, const float* __restrict__ pscore,
    const int* __restrict__ pidx, int* __restrict__ out) {
  const int row = blockIdx.x;
  const int tid = threadIdx.x;
  __shared__ float wbest[4];
  __shared__ int wslot[4];
  __shared__ int winner;
  __shared__ int cand[8];
  __shared__ float fsc[8];
  __shared__ int fid[8];

  float s = pscore[(size_t)row * 256 + tid];
  const int id = pidx[(size_t)row * 256 + tid];

  for (int it = 0; it < 8; it++) {
    float bs = s;
    int bslot = tid;
#pragma unroll
    for (int m = 32; m >= 1; m >>= 1) {
      const float os = __shfl_xor(bs, m, 64);
      const int oslot = __shfl_xor(bslot, m, 64);
      if (os > bs || (os == bs && oslot < bslot)) { bs = os; bslot = oslot; }
    }
    if ((tid & 63) == 0) { wbest[tid >> 6] = bs; wslot[tid >> 6] = bslot; }
    __syncthreads();
    if (tid == 0) {
      float b = wbest[0]; int sl = wslot[0];
      for (int wv = 1; wv < 4; wv++)
        if (wbest[wv] > b || (wbest[wv] == b && wslot[wv] < sl)) { b = wbest[wv]; sl = wslot[wv]; }
      winner = sl;
    }
    __syncthreads();
    if (tid == winner) { cand[it] = id; s = -3.4e38f; }
    __syncthreads();
  }

  const int c = cand[tid >> 5];
  const float* ep = enc + (size_t)row * 512;
  const float* cp = cbn + (size_t)c * 512;
  float dot = 0.0f;
  const int d0 = (tid & 31) * 16;
#pragma unroll
  for (int u = 0; u < 4; u++) {
    const float4 e4 = *(const float4*)(ep + d0 + u * 4);
    const float4 c4 = *(const float4*)(cp + d0 + u * 4);
    dot = fmaf(e4.x, c4.x, dot);
    dot = fmaf(e4.y, c4.y, dot);
    dot = fmaf(e4.z, c4.z, dot);
    dot = fmaf(e4.w, c4.w, dot);
  }
#pragma unroll
  for (int m = 16; m >= 1; m >>= 1) dot += __shfl_xor(dot, m, 64);
  if ((tid & 31) == 0) {
    fsc[tid >> 5] = 2.0f * dot - cb2[c];
    fid[tid >> 5] = c;
  }
  __syncthreads();
  if (tid == 0) {
    float b = fsc[0]; int bi = fid[0];
    for (int q = 1; q < 8; q++)
      if (fsc[q] > b || (fsc[q] == b && fid[q] < bi)) { b = fsc[q]; bi = fid[q]; }
    out[row] = bi;
  }
}

extern "C" void kernel_launch(void* const* d_in, const int* in_sizes, int n_in,
                              void* d_out, int out_size, void* d_ws, size_t ws_size,
                              hipStream_t stream) {
  const float* x = (const float*)d_in[0];    // [16,1024,4096]
  const float* w1 = (const float*)d_in[1];   // [512,1024,3]
  const float* w2 = (const float*)d_in[2];   // [512,512,3]
  const float* cb = (const float*)d_in[3];   // [8192,512]
  int* out = (int*)d_out;                    // [16,1024] int32

  char* w0 = (char*)d_ws;
  const size_t MB = 1ull << 20;
  // Phase 1 (convs):
  ushort* xe1 = (ushort*)(w0);               // [0,128)   16*2048*2048 ush
  ushort* xo1 = (ushort*)(w0 + 128 * MB);    // [128,256.1) 16*2049*2048
  ushort* xe2 = (ushort*)(w0 + 257 * MB);    // [257,289)  16*1024*1024
  ushort* xo2 = (ushort*)(w0 + 289 * MB);    // [289,321.1) 16*1025*1024
  ushort* ws1 = (ushort*)(w0 + 322 * MB);    // 6 MiB
  ushort* ws2 = (ushort*)(w0 + 328 * MB);    // 3 MiB (ends 331 MiB)
  // Phase 2 (reuse [0,256) after conv1 is done):
  float* out2t = (float*)(w0);               // [0,32)
  float* enc = (float*)(w0 + 32 * MB);       // [32,64)
  ushort* enc16 = (ushort*)(w0 + 64 * MB);   // [64,80)
  float* cbn = (float*)(w0 + 80 * MB);       // [80,96)
  ushort* cbn16 = (ushort*)(w0 + 96 * MB);   // [96,104)
  float* cb2 = (float*)(w0 + 104 * MB);      // 32 KiB
  float* pscore = (float*)(w0 + 112 * MB);   // [112,128)
  int* pidx = (int*)(w0 + 128 * MB);         // [128,144) (xo1 dead by then)

  zero_halo<<<16, 256, 0, stream>>>(xo1, xo2);
  prep_w<<<2048, 256, 0, stream>>>(w1, ws1, 512 * 1024);
  prep_w<<<1024, 256, 0, stream>>>(w2, ws2, 512 * 512);
  prep_x<1024, 4096><<<dim3(16, 32, 16), 256, 0, stream>>>(x, xe1, xo1);
  conv_mfma<1024, 2048, true><<<dim3(4, 32, 16), 256, 0, stream>>>(
      xe1, xo1, ws1, nullptr, xe2, xo2);
  conv_mfma<512, 1024, false><<<dim3(4, 16, 16), 256, 0, stream>>>(
      xe2, xo2, ws2, out2t, nullptr, nullptr);
  norm_rows<<<16384, 64, 0, stream>>>(out2t, enc, enc16);
  norm_cb<<<2048, 256, 0, stream>>>(cb, cbn, cbn16, cb2);
  score_top2<<<dim3(64, 128), 256, 0, stream>>>(enc16, cbn16, cb2, pscore, pidx);
  rescore_argmax<<<16384, 256, 0, stream>>>(enc, cbn, cb2, pscore, pidx, out);
}